// Round 3
// baseline (12.757 us; speedup 1.0000x reference)
//
#include <hip/hip_runtime.h>
#include <math.h>

// Gauss2DEffect: per-pixel-sigma horizontal Gaussian blur, f32.
// x: [1,3,1024,1024], sigma: [1,1,1024,1024], out: [1,3,1024,1024]
//
// Round 3: LDS-staged row with replicated edge padding.
//  - block = 1 row (256 threads x 4 pixels); smem[3][1048] = row + 12-float
//    replicated pads on each side -> NO clamp logic, no per-load 64-bit
//    address math: 7 ds_read_b128 per channel off one 32-bit address with
//    immediate offsets.
//  - weights: exp(-i^2/2s^2) = q^(i^2) via recurrence, 1 exp per pixel.

#define HH 1024
#define WW 1024
#define CC 3
#define KK 10
#define PP 4
#define PAD 12
#define ROWLEN (WW + 2 * PAD)   // 1048

__global__ __launch_bounds__(256) void gauss1d_kernel(
    const float* __restrict__ x,
    const float* __restrict__ sigma,
    float* __restrict__ out)
{
    __shared__ float smem[CC][ROWLEN];

    const int tid = threadIdx.x;
    const int h   = blockIdx.x;           // one row per block
    const int w0  = tid * PP;             // first pixel in row, multiple of 4
    const int p0  = h * WW + w0;          // global pixel index

    // ---- stage the 3 channel rows into LDS with replicated edges ----
    float4 lv[CC];
    #pragma unroll
    for (int c = 0; c < CC; ++c)
        lv[c] = *reinterpret_cast<const float4*>(x + c * (HH * WW) + h * WW + w0);
    const float4 sg4 = *reinterpret_cast<const float4*>(sigma + p0);

    #pragma unroll
    for (int c = 0; c < CC; ++c)
        *reinterpret_cast<float4*>(&smem[c][PAD + w0]) = lv[c];
    if (tid == 0) {
        #pragma unroll
        for (int c = 0; c < CC; ++c) {
            const float e = lv[c].x;
            const float4 pv = {e, e, e, e};
            *reinterpret_cast<float4*>(&smem[c][0]) = pv;
            *reinterpret_cast<float4*>(&smem[c][4]) = pv;
            *reinterpret_cast<float4*>(&smem[c][8]) = pv;
        }
    }
    if (tid == 255) {
        #pragma unroll
        for (int c = 0; c < CC; ++c) {
            const float e = lv[c].w;
            const float4 pv = {e, e, e, e};
            *reinterpret_cast<float4*>(&smem[c][PAD + WW + 0]) = pv;
            *reinterpret_cast<float4*>(&smem[c][PAD + WW + 4]) = pv;
            *reinterpret_cast<float4*>(&smem[c][PAD + WW + 8]) = pv;
        }
    }

    // ---- per-pixel weights (overlaps staging latency) ----
    const float sgs[PP] = {sg4.x, sg4.y, sg4.z, sg4.w};
    float wts[PP][KK + 1];
    float inv_norm[PP];
    #pragma unroll
    for (int p = 0; p < PP; ++p) {
        const float sig = sgs[p];
        const float inv2s2 = __builtin_amdgcn_rcpf(2.0f * sig * sig);
        const float hs = ceilf(2.0f * sig);          // half_step
        const float q = __expf(-inv2s2);             // q = exp(-1/(2s^2))
        const float q2 = q * q;
        float wp = 1.0f;   // gated w_{i-1}
        float tq = q;      // q^(2i-1)
        float norm = 1.0f;
        wts[p][0] = 1.0f;
        #pragma unroll
        for (int i = 1; i <= KK; ++i) {
            float wi = wp * tq;                      // q^(i^2) until gated
            tq *= q2;
            wi = ((float)i <= hs) ? wi : 0.0f;       // half_step gate
            wts[p][i] = wi;
            norm += 2.0f * wi;
            wp = wi;
        }
        inv_norm[p] = __builtin_amdgcn_rcpf(norm);   // norm >= 1 (center tap)
    }

    __syncthreads();

    // ---- compute: 28-float register window per channel from LDS ----
    // window covers row positions [w0-12, w0+15] -> smem index [w0, w0+27],
    // 16B-aligned base, 7 ds_read_b128 with immediate offsets.
    #pragma unroll
    for (int c = 0; c < CC; ++c) {
        float v[28];
        #pragma unroll
        for (int k = 0; k < 7; ++k) {
            const float4 rv = *reinterpret_cast<const float4*>(&smem[c][w0 + 4 * k]);
            v[4 * k + 0] = rv.x; v[4 * k + 1] = rv.y;
            v[4 * k + 2] = rv.z; v[4 * k + 3] = rv.w;
        }
        float4 res;
        float* rp = reinterpret_cast<float*>(&res);
        #pragma unroll
        for (int p = 0; p < PP; ++p) {
            const int o = PAD + p;                   // center index in window
            float acc = v[o];                        // w0 == 1
            #pragma unroll
            for (int i = 1; i <= KK; ++i)
                acc += wts[p][i] * (v[o - i] + v[o + i]);
            rp[p] = acc * inv_norm[p];
        }
        *reinterpret_cast<float4*>(out + c * (HH * WW) + p0) = res;
    }
}

extern "C" void kernel_launch(void* const* d_in, const int* in_sizes, int n_in,
                              void* d_out, int out_size, void* d_ws, size_t ws_size,
                              hipStream_t stream) {
    const float* x = (const float*)d_in[0];
    const float* sigma = (const float*)d_in[1];
    float* out = (float*)d_out;

    const int grid = HH;        // one row per block
    const int block = 256;      // 4 pixels per thread
    gauss1d_kernel<<<grid, block, 0, stream>>>(x, sigma, out);
}